// Round 10
// baseline (155.048 us; speedup 1.0000x reference)
//
#include <hip/hip_runtime.h>
#include <hip/hip_cooperative_groups.h>
#include <math.h>
#include <stdint.h>

namespace cg = cooperative_groups;

#define B_ 4
#define T_ 64000
#define H_ 96
#define NCH 1000
#define TT_ 64
#define TWO_PI_D 6.283185307179586

typedef float2 cplx;
__device__ __forceinline__ cplx cadd(cplx a, cplx b){ return make_float2(a.x+b.x, a.y+b.y); }
__device__ __forceinline__ cplx csub(cplx a, cplx b){ return make_float2(a.x-b.x, a.y-b.y); }
__device__ __forceinline__ cplx cmul(cplx a, cplx b){ return make_float2(a.x*b.x - a.y*b.y, a.x*b.y + a.y*b.x); }

// ---------------- static scratch ----------------
__device__ double g_dp[B_*T_];
__device__ unsigned char g_hcnt[B_*T_];
__device__ float  g_signal[B_*T_];
__device__ float  g_shaped[B_*T_];
__device__ float2 g_W1[2*512*125];
__device__ float2 g_Z[2*125*512];
__device__ double g_chunksum[B_*NCH];
__device__ double g_stats[B_*2];
__device__ double g_part[B_*250*2];

// ---------------- threefry (partitionable, out0^out1) ----------------
__device__ __forceinline__ uint32_t rotl32(uint32_t x, int r){ return (x<<r)|(x>>(32-r)); }

__device__ __forceinline__ uint32_t threefry_bits(uint32_t i){
  uint32_t x0 = 0u, x1 = i;
  const uint32_t ks0 = 0u, ks1 = 42u, ks2 = 0u ^ 42u ^ 0x1BD11BDAu;
  x0 += ks0; x1 += ks1;
  #define TFR(r) { x0 += x1; x1 = rotl32(x1, r); x1 ^= x0; }
  TFR(13) TFR(15) TFR(26) TFR(6)   x0 += ks1; x1 += ks2 + 1u;
  TFR(17) TFR(29) TFR(16) TFR(24)  x0 += ks2; x1 += ks0 + 2u;
  TFR(13) TFR(15) TFR(26) TFR(6)   x0 += ks0; x1 += ks1 + 3u;
  TFR(17) TFR(29) TFR(16) TFR(24)  x0 += ks1; x1 += ks2 + 4u;
  TFR(13) TFR(15) TFR(26) TFR(6)   x0 += ks2; x1 += ks0 + 5u;
  #undef TFR
  return x0 ^ x1;
}

__device__ __forceinline__ float bits_to_normal(uint32_t bits){
  uint32_t mbits = (bits >> 9) | 0x3F800000u;
  float f = __uint_as_float(mbits) - 1.0f;
  const float lo = -0.99999994f;
  float x = f * 2.0f + lo;
  x = fmaxf(lo, x);
  float w = -log1pf(-x*x);
  float p;
  if (w < 5.0f){
    w -= 2.5f;
    p = 2.81022636e-08f;
    p = fmaf(p, w, 3.43273939e-07f);
    p = fmaf(p, w, -3.5233877e-06f);
    p = fmaf(p, w, -4.39150654e-06f);
    p = fmaf(p, w, 0.00021858087f);
    p = fmaf(p, w, -0.00125372503f);
    p = fmaf(p, w, -0.00417768164f);
    p = fmaf(p, w, 0.246640727f);
    p = fmaf(p, w, 1.50140941f);
  } else {
    w = sqrtf(w) - 3.0f;
    p = -0.000200214257f;
    p = fmaf(p, w, 0.000100950558f);
    p = fmaf(p, w, 0.00134934322f);
    p = fmaf(p, w, -0.00367342844f);
    p = fmaf(p, w, 0.00573950773f);
    p = fmaf(p, w, -0.0076224613f);
    p = fmaf(p, w, 0.00943887047f);
    p = fmaf(p, w, 1.00167406f);
    p = fmaf(p, w, 2.83297682f);
  }
  return 1.4142135623730951f * (p * x);
}

__constant__ int KSZc[8] = {129,91,65,45,33,23,17,11};

// ---------------- prep: breath(noise+kern+conv+stats partial) + phase increments ----------------
__global__ __launch_bounds__(256) void k_prep(const float* __restrict__ bss,
                                              const float* __restrict__ f0,
                                              const float* __restrict__ vr,
                                              const float* __restrict__ vd){
  int b = blockIdx.x / 250, c = blockIdx.x % 250;
  int t0 = c*256, tid = threadIdx.x;
  __shared__ float ns[384];
  __shared__ float kl[129];
  __shared__ float wn[8];
  if (tid < 8){
    int ksz = KSZc[tid];
    float sig = (float)ksz / 6.0f;
    float inv2s2 = 1.0f/(2.0f*sig*sig);
    int ctr = ksz>>1;
    float s = 0.f;
    for (int j=0;j<ksz;j++){ float d = (float)(j - ctr); s += expf(-d*d*inv2s2); }
    wn[tid] = bss[((size_t)b*T_ + T_/2)*8 + tid] / s;
  }
  for (int j = tid; j < 384; j += 256){
    int t = t0 - 64 + j;
    float v = 0.f;
    if (t >= 0 && t < T_) v = bits_to_normal(threefry_bits((uint32_t)(b*T_ + t)));
    ns[j] = v;
  }
  __syncthreads();
  if (tid < 129){
    int tau = tid - 64;
    float acc = 0.f;
    #pragma unroll
    for (int i=0;i<8;i++){
      int ksz = KSZc[i]; int hw = ksz>>1;
      if (tau >= -hw && tau <= hw){
        float sig = (float)ksz/6.0f;
        float inv2s2 = 1.0f/(2.0f*sig*sig);
        acc += expf(-(float)(tau*tau)*inv2s2) * wn[i];
      }
    }
    kl[tid] = acc;
  }
  __syncthreads();
  float acc = 0.f;
  for (int j=0;j<129;j++) acc = fmaf(ns[tid+j], kl[j], acc);
  g_shaped[b*T_ + t0 + tid] = acc;
  double xx = (double)acc;
  double s1 = xx, s2 = xx*xx;
  for (int o=1;o<64;o<<=1){ s1 += __shfl_down(s1,o); s2 += __shfl_down(s2,o); }
  __shared__ double a1[4], a2[4];
  int lane = tid&63, wid = tid>>6;
  if (lane==0){ a1[wid]=s1; a2[wid]=s2; }
  __syncthreads();
  if (tid==0){
    g_part[(b*250+c)*2]   = a1[0]+a1[1]+a1[2]+a1[3];
    g_part[(b*250+c)*2+1] = a2[0]+a2[1]+a2[2]+a2[3];
  }
  // ---- phase increments + harmonic count + 64-chunk sums ----
  int t = t0 + tid;
  int idx = b*T_ + t;
  double tt = (double)t / 44100.0;
  double sv = sin(TWO_PI_D * (double)vr[idx] * tt);
  double lm = (double)vd[idx] * 0.057762265046662105;   // ln2/12
  double vm = exp(sv * lm);
  double f0s = (double)f0[idx];
  double f0v = (f0s > 0.0) ? f0s * vm : f0s;
  int cnt;
  if (f0v <= 0.0) cnt = 96;
  else {
    int n = (int)(22050.0 / f0v);
    if (!((double)n * f0v < 22050.0)) n--;
    if ((double)(n+1) * f0v < 22050.0) n++;
    cnt = (n < 0) ? 0 : ((n > 96) ? 96 : n);
  }
  g_hcnt[idx] = (unsigned char)cnt;
  double v = TWO_PI_D * f0v / 44100.0;
  g_dp[idx] = v;
  for (int o=1;o<64;o<<=1) v += __shfl_down(v, o);
  if (lane == 0) g_chunksum[b*NCH + c*4 + wid] = v;
}

// ---------------- harmonic additive synth (self-scan fused) ----------------
__global__ __launch_bounds__(256) void k_signal(const float* __restrict__ amps,
                                                const float* __restrict__ goq,
                                                const float* __restrict__ iph,
                                                float* __restrict__ out_final){
  __shared__ __align__(16) float As[TT_*100];
  __shared__ float ph[TT_];
  int b = blockIdx.x / NCH, c = blockIdx.x % NCH;
  int t0 = c*TT_;
  int tid = threadIdx.x;
  if (tid < 64){
    // chunk-prefix: sum chunksums[0..c) lane-strided + xor-tree
    double s = 0.0;
    for (int ch = tid; ch < c; ch += 64) s += g_chunksum[b*NCH + ch];
    for (int o=1;o<64;o<<=1) s += __shfl_xor(s, o);
    double base = s + (double)iph[b];
    int idx = b*T_ + t0 + tid;
    double v = g_dp[idx];
    for (int o=1;o<64;o<<=1){ double u = __shfl_up(v, o); if (tid >= o) v += u; }
    ph[tid] = (float)fmod(base + v, TWO_PI_D);
    if (c == NCH-1 && tid == 63) out_final[b] = (float)fmod(base + v, TWO_PI_D);
  }
  const float4* ag = (const float4*)(amps + ((size_t)b*T_ + t0)*H_);
  for (int i4 = tid; i4 < TT_*H_/4; i4 += 256){
    int row = i4 / 24, col4 = i4 - row*24;
    float4 v = ag[i4];
    *((float4*)&As[row*100 + col4*4]) = v;
  }
  __syncthreads();
  int tl = tid >> 2, part = tid & 3;
  int idx = b*T_ + t0 + tl;
  float r = ph[tl];
  int hc = (int)g_hcnt[idx];
  float oq = goq[idx];
  float k1 = 1.57079632679f / oq;
  float k2 = 1.57079632679f / (1.0f - oq);
  float sum = 0.f;
  const float4* Ar = (const float4*)&As[tl*100 + part*24];
  #pragma unroll
  for (int j4=0;j4<6;j4++){
    float4 a4 = Ar[j4];
    float av0[4] = {a4.x, a4.y, a4.z, a4.w};
    #pragma unroll
    for (int e=0;e<4;e++){
      int h = part*24 + j4*4 + e;
      float nn = (float)(h+1);
      float amp = (h < hc) ? av0[e] : 0.0f;
      float fr = r * nn * 0.15915494309189535f;
      fr = fr - floorf(fr);
      float a1 = fr * k1;
      float a2 = (fr - oq) * k2;
      float s = __sinf(a1);
      float cc = __cosf(a2);
      float v = (fr < oq) ? s*s : cc*cc;
      sum = fmaf(v - 0.5f, amp, sum);
    }
  }
  sum += __shfl_xor(sum, 1);
  sum += __shfl_xor(sum, 2);
  if (part == 0) g_signal[idx] = sum;
}

// ---------------- FFT helpers ----------------
template<int SGN>
__device__ __forceinline__ float2* fft512_stages(float2* bufA, float2* bufB, int tid){
  float2* src = bufA; float2* dst = bufB;
  #pragma unroll
  for (int st=0; st<9; st++){
    const int s = 1<<st;
    const int n = 512>>st;
    const int m = n>>1;
    int p = tid >> st;
    int q = tid & (s-1);
    float2 a  = src[q + s*p];
    float2 bb = src[q + s*(p+m)];
    float ang = (float)SGN * ((float)(2.0*M_PI)/(float)n) * (float)p;
    float sw, cw; __sincosf(ang, &sw, &cw);
    dst[q + 2*s*p]     = cadd(a, bb);
    dst[q + 2*s*p + s] = cmul(make_float2(cw, sw), csub(a, bb));
    __syncthreads();
    float2* tp = src; src = dst; dst = tp;
  }
  return src;
}

__device__ __forceinline__ cplx w5k(int k, float sgn){
  const float C[5] = {1.f, 0.30901699f, -0.80901699f, -0.80901699f, 0.30901699f};
  const float S[5] = {0.f, 0.95105652f, 0.58778525f, -0.58778525f, -0.95105652f};
  return make_float2(C[k], sgn*S[k]);
}

template<int SGN>
__device__ __forceinline__ float2* fft125_rows(float2* bufA, float2* bufB, int tid){
  float2* src = bufA; float2* dst = bufB;
  #pragma unroll
  for (int st=0; st<3; st++){
    const int s = (st==0)?1:((st==1)?5:25);
    const int n = (st==0)?125:((st==1)?25:5);
    const int m = n/5;
    if (tid < 200){
      int row = tid/25, w = tid - row*25;
      int p = w/s, q = w - p*s;
      int base = row*125 + q;
      float2 a0 = src[base + s*p];
      float2 a1 = src[base + s*(p+m)];
      float2 a2 = src[base + s*(p+2*m)];
      float2 a3 = src[base + s*(p+3*m)];
      float2 a4 = src[base + s*(p+4*m)];
      #pragma unroll
      for (int r2=0;r2<5;r2++){
        float2 acc = a0;
        acc = cadd(acc, cmul(a1, w5k((1*r2)%5, (float)SGN)));
        acc = cadd(acc, cmul(a2, w5k((2*r2)%5, (float)SGN)));
        acc = cadd(acc, cmul(a3, w5k((3*r2)%5, (float)SGN)));
        acc = cadd(acc, cmul(a4, w5k((4*r2)%5, (float)SGN)));
        float ang = (float)SGN * ((float)(2.0*M_PI)/(float)n) * (float)(p*r2);
        float sw,cw; __sincosf(ang,&sw,&cw);
        dst[base + s*(5*p+r2)] = cmul(make_float2(cw,sw), acc);
      }
    }
    __syncthreads();
    float2* tp = src; src = dst; dst = tp;
  }
  return src;
}

// ---------------- one cooperative kernel: fwd + stats | mid | inv + mix ----------------
__global__ __launch_bounds__(256) void k_fft(const float* __restrict__ ffq,
                                             const float* __restrict__ fbw,
                                             const float* __restrict__ fgn,
                                             const float* __restrict__ brth,
                                             float* __restrict__ outp){
  cg::grid_group grid = cg::this_grid();
  __shared__ float2 smem[2000];
  int blk = blockIdx.x;
  int tid = threadIdx.x;

  // ---- phase 0: forward 512-FFT (all 250 blocks) + stats final (blocks 0..3) ----
  {
    int p = blk / 125, n1 = blk % 125;
    float2* bufA = smem;
    float2* bufB = smem + 512;
    const float* sa = g_signal + (size_t)(2*p)*T_;
    const float* sb = g_signal + (size_t)(2*p+1)*T_;
    for (int i=tid;i<512;i+=256) bufA[i] = make_float2(sa[n1 + 125*i], sb[n1 + 125*i]);
    __syncthreads();
    float2* res = fft512_stages<-1>(bufA, bufB, tid);
    for (int i=tid;i<512;i+=256){
      float ang = -(float)(2.0*M_PI/64000.0) * (float)(n1*i);
      float sw,cw; __sincosf(ang,&sw,&cw);
      g_W1[((size_t)p*512 + i)*125 + n1] = cmul(make_float2(cw,sw), res[i]);
    }
    if (blk < B_){
      int b = blk;
      double s1=0.0, s2=0.0;
      if (tid < 250){ s1 = g_part[(b*250+tid)*2]; s2 = g_part[(b*250+tid)*2+1]; }
      for (int o=1;o<64;o<<=1){ s1 += __shfl_down(s1,o); s2 += __shfl_down(s2,o); }
      __shared__ double a1[4], a2[4];
      int lane = tid&63, wid = tid>>6;
      if (lane==0){ a1[wid]=s1; a2[wid]=s2; }
      __syncthreads();
      if (tid==0){
        double S1=a1[0]+a1[1]+a1[2]+a1[3], S2=a2[0]+a2[1]+a2[2]+a2[3];
        double mean = S1 / (double)T_;
        double var = (S2 - (double)T_*mean*mean) / (double)(T_-1);
        if (var < 0.0) var = 0.0;
        double rstd = 1.0/(sqrt(var) + 1e-8);
        g_stats[b*2] = mean; g_stats[b*2+1] = rstd;
      }
    }
  }
  grid.sync();

  // ---- phase 1: 125-FFT + filter + inverse-125 (blocks 0..127) ----
  if (blk < 128){
    int p = blk / 64;
    int j = blk % 64;
    float2* bufA = smem;
    float2* bufB = smem + 1000;
    int k2r[8];
    #pragma unroll
    for (int l=0;l<8;l++){
      int k2;
      if (l < 4) k2 = 4*j + l;
      else if (j==0 && l==4) k2 = 256;
      else k2 = 512 - 4*j - (l-4);
      k2r[l] = k2;
    }
    for (int i=tid;i<1000;i+=256){
      int l = i/125, n1 = i - l*125;
      bufA[i] = g_W1[((size_t)p*512 + k2r[l])*125 + n1];
    }
    float fca[4], bwa[4], ga[4], fcb[4], bwb[4], gb[4];
    int ba = 2*p, bb = 2*p+1;
    #pragma unroll
    for (int q=0;q<4;q++){
      size_t ia = ((size_t)ba*T_ + T_/2)*4 + q;
      size_t ib = ((size_t)bb*T_ + T_/2)*4 + q;
      fca[q]=ffq[ia]; bwa[q]=fbw[ia]; ga[q]=fgn[ia];
      fcb[q]=ffq[ib]; bwb[q]=fbw[ib]; gb[q]=fgn[ib];
    }
    __syncthreads();
    float2* X = fft125_rows<-1>(bufA, bufB, tid);
    float2* Y = (X == bufA) ? bufB : bufA;
    for (int i=tid;i<1000;i+=256){
      int l = i/125, k1 = i - l*125;
      int k2 = k2r[l];
      int lm = ((j==0) && (l==0 || l==4)) ? l : (l^4);
      int k1m = (k2 == 0) ? ((k1==0)?0:(125-k1)) : (124-k1);
      float2 Z1 = X[l*125 + k1];
      float2 Z2 = X[lm*125 + k1m];
      float xax = 0.5f*(Z1.x + Z2.x), xay = 0.5f*(Z1.y - Z2.y);
      float xbx = 0.5f*(Z1.y + Z2.y), xby = -0.5f*(Z1.x - Z2.x);
      int f = k2 + 512*k1;
      int fi = (f <= 32000) ? f : (64000 - f);
      float freq = (float)fi * 0.6890625f;
      float ra = 0.f, rb = 0.f;
      #pragma unroll
      for (int q=0;q<4;q++){
        float da = (freq - fca[q]) / (bwa[q]*0.5f);
        ra += ga[q] / (1.0f + da*da);
        float db = (freq - fcb[q]) / (bwb[q]*0.5f);
        rb += gb[q] / (1.0f + db*db);
      }
      float yax = ra*xax, yay = ra*xay;
      float ybx = rb*xbx, yby = rb*xby;
      Y[i] = make_float2(yax - yby, yay + ybx);
    }
    __syncthreads();
    float2* res2 = fft125_rows<1>(Y, X, tid);
    for (int i=tid;i<1000;i+=256){
      int l = i/125, n1 = i - l*125;
      int k2 = k2r[l];
      float ang = (float)(2.0*M_PI/64000.0) * (float)(n1*k2);
      float sw,cw; __sincosf(ang,&sw,&cw);
      g_Z[((size_t)p*125 + n1)*512 + k2] = cmul(make_float2(cw,sw), res2[i]);
    }
  }
  grid.sync();

  // ---- phase 2: inverse 512-FFT + epilogue mix (all 250 blocks) ----
  {
    int p = blk / 125, n1 = blk % 125;
    float2* bufA = smem;
    float2* bufB = smem + 512;
    const float2* gin = g_Z + ((size_t)p*125 + n1)*512;
    for (int i=tid;i<512;i+=256) bufA[i] = gin[i];
    __syncthreads();
    float2* res = fft512_stages<1>(bufA, bufB, tid);
    int ba = 2*p, bb = 2*p+1;
    float mean_a = (float)g_stats[ba*2], rstd_a = (float)g_stats[ba*2+1];
    float mean_b = (float)g_stats[bb*2], rstd_b = (float)g_stats[bb*2+1];
    for (int i=tid;i<512;i+=256){
      int t = n1 + 125*i;
      float2 v = res[i];
      {
        int idx = ba*T_ + t;
        float filt = v.x * (1.0f/64000.0f);
        float br = brth[idx];
        float breath = (g_shaped[idx] - mean_a) * rstd_a;
        outp[idx] = filt*(1.0f - br) + breath*br;
      }
      {
        int idx = bb*T_ + t;
        float filt = v.y * (1.0f/64000.0f);
        float br = brth[idx];
        float breath = (g_shaped[idx] - mean_b) * rstd_b;
        outp[idx] = filt*(1.0f - br) + breath*br;
      }
    }
  }
}

extern "C" void kernel_launch(void* const* d_in, const int* in_sizes, int n_in,
                              void* d_out, int out_size, void* d_ws, size_t ws_size,
                              hipStream_t stream){
  (void)in_sizes; (void)n_in; (void)out_size; (void)d_ws; (void)ws_size;
  const float* f0   = (const float*)d_in[0];
  const float* amps = (const float*)d_in[1];
  const float* vr   = (const float*)d_in[2];
  const float* vd   = (const float*)d_in[3];
  const float* ffq  = (const float*)d_in[4];
  const float* fbw  = (const float*)d_in[5];
  const float* fgn  = (const float*)d_in[6];
  const float* goq  = (const float*)d_in[7];
  const float* brth = (const float*)d_in[9];
  const float* bss  = (const float*)d_in[10];
  const float* iph  = (const float*)d_in[11];
  float* out = (float*)d_out;
  float* out_final = out + (size_t)B_*T_;

  k_prep<<<B_*250,256,0,stream>>>(bss, f0, vr, vd);
  k_signal<<<B_*NCH,256,0,stream>>>(amps, goq, iph, out_final);
  void* fargs[] = { (void*)&ffq, (void*)&fbw, (void*)&fgn, (void*)&brth, (void*)&out };
  hipLaunchCooperativeKernel((const void*)k_fft, dim3(250), dim3(256), fargs, 0, stream);
}

// Round 11
// 78.626 us; speedup vs baseline: 1.9720x; 1.9720x over previous
//
#include <hip/hip_runtime.h>
#include <math.h>
#include <stdint.h>

#define B_ 4
#define T_ 64000
#define H_ 96
#define NCH 1000
#define TT_ 64
#define TWO_PI_D 6.283185307179586

typedef float2 cplx;
__device__ __forceinline__ cplx cadd(cplx a, cplx b){ return make_float2(a.x+b.x, a.y+b.y); }
__device__ __forceinline__ cplx csub(cplx a, cplx b){ return make_float2(a.x-b.x, a.y-b.y); }
__device__ __forceinline__ cplx cmul(cplx a, cplx b){ return make_float2(a.x*b.x - a.y*b.y, a.x*b.y + a.y*b.x); }

// ---------------- static scratch ----------------
__device__ double g_dp[B_*T_];
__device__ unsigned char g_hcnt[B_*T_];
__device__ float  g_signal[B_*T_];
__device__ float  g_shaped[B_*T_];
__device__ float2 g_W1[2*512*125];
__device__ float2 g_Z[2*125*512];
__device__ double g_chunksum[B_*NCH];
__device__ double g_stats[B_*2];
__device__ double g_part[B_*250*2];

// ---------------- threefry (partitionable, out0^out1) ----------------
__device__ __forceinline__ uint32_t rotl32(uint32_t x, int r){ return (x<<r)|(x>>(32-r)); }

__device__ __forceinline__ uint32_t threefry_bits(uint32_t i){
  uint32_t x0 = 0u, x1 = i;
  const uint32_t ks0 = 0u, ks1 = 42u, ks2 = 0u ^ 42u ^ 0x1BD11BDAu;
  x0 += ks0; x1 += ks1;
  #define TFR(r) { x0 += x1; x1 = rotl32(x1, r); x1 ^= x0; }
  TFR(13) TFR(15) TFR(26) TFR(6)   x0 += ks1; x1 += ks2 + 1u;
  TFR(17) TFR(29) TFR(16) TFR(24)  x0 += ks2; x1 += ks0 + 2u;
  TFR(13) TFR(15) TFR(26) TFR(6)   x0 += ks0; x1 += ks1 + 3u;
  TFR(17) TFR(29) TFR(16) TFR(24)  x0 += ks1; x1 += ks2 + 4u;
  TFR(13) TFR(15) TFR(26) TFR(6)   x0 += ks2; x1 += ks0 + 5u;
  #undef TFR
  return x0 ^ x1;
}

__device__ __forceinline__ float bits_to_normal(uint32_t bits){
  uint32_t mbits = (bits >> 9) | 0x3F800000u;
  float f = __uint_as_float(mbits) - 1.0f;
  const float lo = -0.99999994f;
  float x = f * 2.0f + lo;
  x = fmaxf(lo, x);
  float w = -log1pf(-x*x);
  float p;
  if (w < 5.0f){
    w -= 2.5f;
    p = 2.81022636e-08f;
    p = fmaf(p, w, 3.43273939e-07f);
    p = fmaf(p, w, -3.5233877e-06f);
    p = fmaf(p, w, -4.39150654e-06f);
    p = fmaf(p, w, 0.00021858087f);
    p = fmaf(p, w, -0.00125372503f);
    p = fmaf(p, w, -0.00417768164f);
    p = fmaf(p, w, 0.246640727f);
    p = fmaf(p, w, 1.50140941f);
  } else {
    w = sqrtf(w) - 3.0f;
    p = -0.000200214257f;
    p = fmaf(p, w, 0.000100950558f);
    p = fmaf(p, w, 0.00134934322f);
    p = fmaf(p, w, -0.00367342844f);
    p = fmaf(p, w, 0.00573950773f);
    p = fmaf(p, w, -0.0076224613f);
    p = fmaf(p, w, 0.00943887047f);
    p = fmaf(p, w, 1.00167406f);
    p = fmaf(p, w, 2.83297682f);
  }
  return 1.4142135623730951f * (p * x);
}

__constant__ int KSZc[8] = {129,91,65,45,33,23,17,11};

// ---------------- prep: breath(noise+kern+conv+stats partial) + phase increments ----------------
__global__ __launch_bounds__(256) void k_prep(const float* __restrict__ bss,
                                              const float* __restrict__ f0,
                                              const float* __restrict__ vr,
                                              const float* __restrict__ vd){
  int b = blockIdx.x / 250, c = blockIdx.x % 250;
  int t0 = c*256, tid = threadIdx.x;
  __shared__ float ns[384];
  __shared__ float kl[129];
  __shared__ float wn[8];
  if (tid < 8){
    int ksz = KSZc[tid];
    float sig = (float)ksz / 6.0f;
    float inv2s2 = 1.0f/(2.0f*sig*sig);
    int ctr = ksz>>1;
    float s = 0.f;
    for (int j=0;j<ksz;j++){ float d = (float)(j - ctr); s += expf(-d*d*inv2s2); }
    wn[tid] = bss[((size_t)b*T_ + T_/2)*8 + tid] / s;
  }
  for (int j = tid; j < 384; j += 256){
    int t = t0 - 64 + j;
    float v = 0.f;
    if (t >= 0 && t < T_) v = bits_to_normal(threefry_bits((uint32_t)(b*T_ + t)));
    ns[j] = v;
  }
  __syncthreads();
  if (tid < 129){
    int tau = tid - 64;
    float acc = 0.f;
    #pragma unroll
    for (int i=0;i<8;i++){
      int ksz = KSZc[i]; int hw = ksz>>1;
      if (tau >= -hw && tau <= hw){
        float sig = (float)ksz/6.0f;
        float inv2s2 = 1.0f/(2.0f*sig*sig);
        acc += expf(-(float)(tau*tau)*inv2s2) * wn[i];
      }
    }
    kl[tid] = acc;
  }
  __syncthreads();
  float acc = 0.f;
  for (int j=0;j<129;j++) acc = fmaf(ns[tid+j], kl[j], acc);
  g_shaped[b*T_ + t0 + tid] = acc;
  double xx = (double)acc;
  double s1 = xx, s2 = xx*xx;
  for (int o=1;o<64;o<<=1){ s1 += __shfl_down(s1,o); s2 += __shfl_down(s2,o); }
  __shared__ double a1[4], a2[4];
  int lane = tid&63, wid = tid>>6;
  if (lane==0){ a1[wid]=s1; a2[wid]=s2; }
  __syncthreads();
  if (tid==0){
    g_part[(b*250+c)*2]   = a1[0]+a1[1]+a1[2]+a1[3];
    g_part[(b*250+c)*2+1] = a2[0]+a2[1]+a2[2]+a2[3];
  }
  // ---- phase increments + harmonic count + 64-chunk sums ----
  int t = t0 + tid;
  int idx = b*T_ + t;
  double tt = (double)t / 44100.0;
  double sv = sin(TWO_PI_D * (double)vr[idx] * tt);
  double lm = (double)vd[idx] * 0.057762265046662105;   // ln2/12
  double vm = exp(sv * lm);
  double f0s = (double)f0[idx];
  double f0v = (f0s > 0.0) ? f0s * vm : f0s;
  int cnt;
  if (f0v <= 0.0) cnt = 96;
  else {
    int n = (int)(22050.0 / f0v);
    if (!((double)n * f0v < 22050.0)) n--;
    if ((double)(n+1) * f0v < 22050.0) n++;
    cnt = (n < 0) ? 0 : ((n > 96) ? 96 : n);
  }
  g_hcnt[idx] = (unsigned char)cnt;
  double v = TWO_PI_D * f0v / 44100.0;
  g_dp[idx] = v;
  for (int o=1;o<64;o<<=1) v += __shfl_down(v, o);
  if (lane == 0) g_chunksum[b*NCH + c*4 + wid] = v;
}

// ---------------- harmonic additive synth (self-scan fused) ----------------
__global__ __launch_bounds__(256) void k_signal(const float* __restrict__ amps,
                                                const float* __restrict__ goq,
                                                const float* __restrict__ iph,
                                                float* __restrict__ out_final){
  __shared__ __align__(16) float As[TT_*100];
  __shared__ float ph[TT_];
  int b = blockIdx.x / NCH, c = blockIdx.x % NCH;
  int t0 = c*TT_;
  int tid = threadIdx.x;
  if (tid < 64){
    double s = 0.0;
    for (int ch = tid; ch < c; ch += 64) s += g_chunksum[b*NCH + ch];
    for (int o=1;o<64;o<<=1) s += __shfl_xor(s, o);
    double base = s + (double)iph[b];
    int idx = b*T_ + t0 + tid;
    double v = g_dp[idx];
    for (int o=1;o<64;o<<=1){ double u = __shfl_up(v, o); if (tid >= o) v += u; }
    ph[tid] = (float)fmod(base + v, TWO_PI_D);
    if (c == NCH-1 && tid == 63) out_final[b] = (float)fmod(base + v, TWO_PI_D);
  }
  const float4* ag = (const float4*)(amps + ((size_t)b*T_ + t0)*H_);
  for (int i4 = tid; i4 < TT_*H_/4; i4 += 256){
    int row = i4 / 24, col4 = i4 - row*24;
    float4 v = ag[i4];
    *((float4*)&As[row*100 + col4*4]) = v;
  }
  __syncthreads();
  int tl = tid >> 2, part = tid & 3;
  int idx = b*T_ + t0 + tl;
  float r = ph[tl];
  int hc = (int)g_hcnt[idx];
  float oq = goq[idx];
  float k1 = 1.57079632679f / oq;
  float k2 = 1.57079632679f / (1.0f - oq);
  float sum = 0.f;
  const float4* Ar = (const float4*)&As[tl*100 + part*24];
  #pragma unroll
  for (int j4=0;j4<6;j4++){
    float4 a4 = Ar[j4];
    float av0[4] = {a4.x, a4.y, a4.z, a4.w};
    #pragma unroll
    for (int e=0;e<4;e++){
      int h = part*24 + j4*4 + e;
      float nn = (float)(h+1);
      float amp = (h < hc) ? av0[e] : 0.0f;
      float fr = r * nn * 0.15915494309189535f;
      fr = fr - floorf(fr);
      float a1 = fr * k1;
      float a2 = (fr - oq) * k2;
      float s = __sinf(a1);
      float cc = __cosf(a2);
      float v = (fr < oq) ? s*s : cc*cc;
      sum = fmaf(v - 0.5f, amp, sum);
    }
  }
  sum += __shfl_xor(sum, 1);
  sum += __shfl_xor(sum, 2);
  if (part == 0) g_signal[idx] = sum;
}

// ---------------- FFT helpers ----------------
template<int SGN>
__device__ __forceinline__ float2* fft512_stages(float2* bufA, float2* bufB, int tid){
  float2* src = bufA; float2* dst = bufB;
  #pragma unroll
  for (int st=0; st<9; st++){
    const int s = 1<<st;
    const int n = 512>>st;
    const int m = n>>1;
    int p = tid >> st;
    int q = tid & (s-1);
    float2 a  = src[q + s*p];
    float2 bb = src[q + s*(p+m)];
    float ang = (float)SGN * ((float)(2.0*M_PI)/(float)n) * (float)p;
    float sw, cw; __sincosf(ang, &sw, &cw);
    dst[q + 2*s*p]     = cadd(a, bb);
    dst[q + 2*s*p + s] = cmul(make_float2(cw, sw), csub(a, bb));
    __syncthreads();
    float2* tp = src; src = dst; dst = tp;
  }
  return src;
}

__device__ __forceinline__ cplx w5k(int k, float sgn){
  const float C[5] = {1.f, 0.30901699f, -0.80901699f, -0.80901699f, 0.30901699f};
  const float S[5] = {0.f, 0.95105652f, 0.58778525f, -0.58778525f, -0.95105652f};
  return make_float2(C[k], sgn*S[k]);
}

template<int SGN>
__device__ __forceinline__ float2* fft125_rows(float2* bufA, float2* bufB, int tid){
  float2* src = bufA; float2* dst = bufB;
  #pragma unroll
  for (int st=0; st<3; st++){
    const int s = (st==0)?1:((st==1)?5:25);
    const int n = (st==0)?125:((st==1)?25:5);
    const int m = n/5;
    if (tid < 200){
      int row = tid/25, w = tid - row*25;
      int p = w/s, q = w - p*s;
      int base = row*125 + q;
      float2 a0 = src[base + s*p];
      float2 a1 = src[base + s*(p+m)];
      float2 a2 = src[base + s*(p+2*m)];
      float2 a3 = src[base + s*(p+3*m)];
      float2 a4 = src[base + s*(p+4*m)];
      #pragma unroll
      for (int r2=0;r2<5;r2++){
        float2 acc = a0;
        acc = cadd(acc, cmul(a1, w5k((1*r2)%5, (float)SGN)));
        acc = cadd(acc, cmul(a2, w5k((2*r2)%5, (float)SGN)));
        acc = cadd(acc, cmul(a3, w5k((3*r2)%5, (float)SGN)));
        acc = cadd(acc, cmul(a4, w5k((4*r2)%5, (float)SGN)));
        float ang = (float)SGN * ((float)(2.0*M_PI)/(float)n) * (float)(p*r2);
        float sw,cw; __sincosf(ang,&sw,&cw);
        dst[base + s*(5*p+r2)] = cmul(make_float2(cw,sw), acc);
      }
    }
    __syncthreads();
    float2* tp = src; src = dst; dst = tp;
  }
  return src;
}

__global__ __launch_bounds__(256) void k_fft512_fwd(){
  int p = blockIdx.x / 125, n1 = blockIdx.x % 125;
  int tid = threadIdx.x;
  __shared__ float2 bufA[512];
  __shared__ float2 bufB[512];
  const float* sa = g_signal + (size_t)(2*p)*T_;
  const float* sb = g_signal + (size_t)(2*p+1)*T_;
  for (int i=tid;i<512;i+=256) bufA[i] = make_float2(sa[n1 + 125*i], sb[n1 + 125*i]);
  __syncthreads();
  float2* res = fft512_stages<-1>(bufA, bufB, tid);
  for (int i=tid;i<512;i+=256){
    float ang = -(float)(2.0*M_PI/64000.0) * (float)(n1*i);
    float sw,cw; __sincosf(ang,&sw,&cw);
    g_W1[((size_t)p*512 + i)*125 + n1] = cmul(make_float2(cw,sw), res[i]);
  }
  // stats finalize folded into blocks 0..3
  if (blockIdx.x < B_){
    int b = blockIdx.x;
    double s1=0.0, s2=0.0;
    if (tid < 250){ s1 = g_part[(b*250+tid)*2]; s2 = g_part[(b*250+tid)*2+1]; }
    for (int o=1;o<64;o<<=1){ s1 += __shfl_down(s1,o); s2 += __shfl_down(s2,o); }
    __shared__ double a1[4], a2[4];
    int lane = tid&63, wid = tid>>6;
    if (lane==0){ a1[wid]=s1; a2[wid]=s2; }
    __syncthreads();
    if (tid==0){
      double S1=a1[0]+a1[1]+a1[2]+a1[3], S2=a2[0]+a2[1]+a2[2]+a2[3];
      double mean = S1 / (double)T_;
      double var = (S2 - (double)T_*mean*mean) / (double)(T_-1);
      if (var < 0.0) var = 0.0;
      double rstd = 1.0/(sqrt(var) + 1e-8);
      g_stats[b*2] = mean; g_stats[b*2+1] = rstd;
    }
  }
}

__global__ __launch_bounds__(256) void k_fft125_mid(const float* __restrict__ ffq,
                                                    const float* __restrict__ fbw,
                                                    const float* __restrict__ fgn){
  int p = blockIdx.x / 64;
  int j = blockIdx.x % 64;
  int tid = threadIdx.x;
  __shared__ float2 bufA[1000];
  __shared__ float2 bufB[1000];
  int k2r[8];
  #pragma unroll
  for (int l=0;l<8;l++){
    int k2;
    if (l < 4) k2 = 4*j + l;
    else if (j==0 && l==4) k2 = 256;
    else k2 = 512 - 4*j - (l-4);
    k2r[l] = k2;
  }
  for (int i=tid;i<1000;i+=256){
    int l = i/125, n1 = i - l*125;
    bufA[i] = g_W1[((size_t)p*512 + k2r[l])*125 + n1];
  }
  float fca[4], bwa[4], ga[4], fcb[4], bwb[4], gb[4];
  int ba = 2*p, bb = 2*p+1;
  #pragma unroll
  for (int q=0;q<4;q++){
    size_t ia = ((size_t)ba*T_ + T_/2)*4 + q;
    size_t ib = ((size_t)bb*T_ + T_/2)*4 + q;
    fca[q]=ffq[ia]; bwa[q]=fbw[ia]; ga[q]=fgn[ia];
    fcb[q]=ffq[ib]; bwb[q]=fbw[ib]; gb[q]=fgn[ib];
  }
  __syncthreads();
  float2* X = fft125_rows<-1>(bufA, bufB, tid);
  float2* Y = (X == bufA) ? bufB : bufA;
  for (int i=tid;i<1000;i+=256){
    int l = i/125, k1 = i - l*125;
    int k2 = k2r[l];
    int lm = ((j==0) && (l==0 || l==4)) ? l : (l^4);
    int k1m = (k2 == 0) ? ((k1==0)?0:(125-k1)) : (124-k1);
    float2 Z1 = X[l*125 + k1];
    float2 Z2 = X[lm*125 + k1m];
    float xax = 0.5f*(Z1.x + Z2.x), xay = 0.5f*(Z1.y - Z2.y);
    float xbx = 0.5f*(Z1.y + Z2.y), xby = -0.5f*(Z1.x - Z2.x);
    int f = k2 + 512*k1;
    int fi = (f <= 32000) ? f : (64000 - f);
    float freq = (float)fi * 0.6890625f;
    float ra = 0.f, rb = 0.f;
    #pragma unroll
    for (int q=0;q<4;q++){
      float da = (freq - fca[q]) / (bwa[q]*0.5f);
      ra += ga[q] / (1.0f + da*da);
      float db = (freq - fcb[q]) / (bwb[q]*0.5f);
      rb += gb[q] / (1.0f + db*db);
    }
    float yax = ra*xax, yay = ra*xay;
    float ybx = rb*xbx, yby = rb*xby;
    Y[i] = make_float2(yax - yby, yay + ybx);
  }
  __syncthreads();
  float2* res2 = fft125_rows<1>(Y, X, tid);
  for (int i=tid;i<1000;i+=256){
    int l = i/125, n1 = i - l*125;
    int k2 = k2r[l];
    float ang = (float)(2.0*M_PI/64000.0) * (float)(n1*k2);
    float sw,cw; __sincosf(ang,&sw,&cw);
    g_Z[((size_t)p*125 + n1)*512 + k2] = cmul(make_float2(cw,sw), res2[i]);
  }
}

__global__ __launch_bounds__(256) void k_fft512_inv(const float* __restrict__ brth,
                                                    float* __restrict__ outp){
  int p = blockIdx.x / 125, n1 = blockIdx.x % 125;
  int tid = threadIdx.x;
  __shared__ float2 bufA[512];
  __shared__ float2 bufB[512];
  const float2* gin = g_Z + ((size_t)p*125 + n1)*512;
  for (int i=tid;i<512;i+=256) bufA[i] = gin[i];
  __syncthreads();
  float2* res = fft512_stages<1>(bufA, bufB, tid);
  int ba = 2*p, bb = 2*p+1;
  float mean_a = (float)g_stats[ba*2], rstd_a = (float)g_stats[ba*2+1];
  float mean_b = (float)g_stats[bb*2], rstd_b = (float)g_stats[bb*2+1];
  for (int i=tid;i<512;i+=256){
    int t = n1 + 125*i;
    float2 v = res[i];
    {
      int idx = ba*T_ + t;
      float filt = v.x * (1.0f/64000.0f);
      float br = brth[idx];
      float breath = (g_shaped[idx] - mean_a) * rstd_a;
      outp[idx] = filt*(1.0f - br) + breath*br;
    }
    {
      int idx = bb*T_ + t;
      float filt = v.y * (1.0f/64000.0f);
      float br = brth[idx];
      float breath = (g_shaped[idx] - mean_b) * rstd_b;
      outp[idx] = filt*(1.0f - br) + breath*br;
    }
  }
}

extern "C" void kernel_launch(void* const* d_in, const int* in_sizes, int n_in,
                              void* d_out, int out_size, void* d_ws, size_t ws_size,
                              hipStream_t stream){
  (void)in_sizes; (void)n_in; (void)out_size; (void)d_ws; (void)ws_size;
  const float* f0   = (const float*)d_in[0];
  const float* amps = (const float*)d_in[1];
  const float* vr   = (const float*)d_in[2];
  const float* vd   = (const float*)d_in[3];
  const float* ffq  = (const float*)d_in[4];
  const float* fbw  = (const float*)d_in[5];
  const float* fgn  = (const float*)d_in[6];
  const float* goq  = (const float*)d_in[7];
  const float* brth = (const float*)d_in[9];
  const float* bss  = (const float*)d_in[10];
  const float* iph  = (const float*)d_in[11];
  float* out = (float*)d_out;
  float* out_final = out + (size_t)B_*T_;

  k_prep<<<B_*250,256,0,stream>>>(bss, f0, vr, vd);
  k_signal<<<B_*NCH,256,0,stream>>>(amps, goq, iph, out_final);
  k_fft512_fwd<<<250,256,0,stream>>>();
  k_fft125_mid<<<128,256,0,stream>>>(ffq, fbw, fgn);
  k_fft512_inv<<<250,256,0,stream>>>(brth, out);
}

// Round 12
// 74.660 us; speedup vs baseline: 2.0767x; 1.0531x over previous
//
#include <hip/hip_runtime.h>
#include <math.h>
#include <stdint.h>

#define B_ 4
#define T_ 64000
#define H_ 96
#define NCH 1000
#define TT_ 64
#define TWO_PI_D 6.283185307179586

typedef float2 cplx;
__device__ __forceinline__ cplx cadd(cplx a, cplx b){ return make_float2(a.x+b.x, a.y+b.y); }
__device__ __forceinline__ cplx csub(cplx a, cplx b){ return make_float2(a.x-b.x, a.y-b.y); }
__device__ __forceinline__ cplx cmul(cplx a, cplx b){ return make_float2(a.x*b.x - a.y*b.y, a.x*b.y + a.y*b.x); }

// ---------------- static scratch ----------------
__device__ float  g_dpf[B_*T_];
__device__ unsigned char g_hcnt[B_*T_];
__device__ float  g_signal[B_*T_];
__device__ float  g_shaped[B_*T_];
__device__ float2 g_W1[2*512*125];
__device__ float2 g_Z[2*125*512];
__device__ double g_chunksum[B_*NCH];
__device__ double g_stats[B_*2];
__device__ double g_part[B_*250*2];

// ---------------- threefry (partitionable, out0^out1) ----------------
__device__ __forceinline__ uint32_t rotl32(uint32_t x, int r){ return (x<<r)|(x>>(32-r)); }

__device__ __forceinline__ uint32_t threefry_bits(uint32_t i){
  uint32_t x0 = 0u, x1 = i;
  const uint32_t ks0 = 0u, ks1 = 42u, ks2 = 0u ^ 42u ^ 0x1BD11BDAu;
  x0 += ks0; x1 += ks1;
  #define TFR(r) { x0 += x1; x1 = rotl32(x1, r); x1 ^= x0; }
  TFR(13) TFR(15) TFR(26) TFR(6)   x0 += ks1; x1 += ks2 + 1u;
  TFR(17) TFR(29) TFR(16) TFR(24)  x0 += ks2; x1 += ks0 + 2u;
  TFR(13) TFR(15) TFR(26) TFR(6)   x0 += ks0; x1 += ks1 + 3u;
  TFR(17) TFR(29) TFR(16) TFR(24)  x0 += ks1; x1 += ks2 + 4u;
  TFR(13) TFR(15) TFR(26) TFR(6)   x0 += ks2; x1 += ks0 + 5u;
  #undef TFR
  return x0 ^ x1;
}

__device__ __forceinline__ float bits_to_normal(uint32_t bits){
  uint32_t mbits = (bits >> 9) | 0x3F800000u;
  float f = __uint_as_float(mbits) - 1.0f;
  const float lo = -0.99999994f;
  float x = f * 2.0f + lo;
  x = fmaxf(lo, x);
  float w = -log1pf(-x*x);
  float p;
  if (w < 5.0f){
    w -= 2.5f;
    p = 2.81022636e-08f;
    p = fmaf(p, w, 3.43273939e-07f);
    p = fmaf(p, w, -3.5233877e-06f);
    p = fmaf(p, w, -4.39150654e-06f);
    p = fmaf(p, w, 0.00021858087f);
    p = fmaf(p, w, -0.00125372503f);
    p = fmaf(p, w, -0.00417768164f);
    p = fmaf(p, w, 0.246640727f);
    p = fmaf(p, w, 1.50140941f);
  } else {
    w = sqrtf(w) - 3.0f;
    p = -0.000200214257f;
    p = fmaf(p, w, 0.000100950558f);
    p = fmaf(p, w, 0.00134934322f);
    p = fmaf(p, w, -0.00367342844f);
    p = fmaf(p, w, 0.00573950773f);
    p = fmaf(p, w, -0.0076224613f);
    p = fmaf(p, w, 0.00943887047f);
    p = fmaf(p, w, 1.00167406f);
    p = fmaf(p, w, 2.83297682f);
  }
  return 1.4142135623730951f * (p * x);
}

__constant__ int KSZc[8] = {129,91,65,45,33,23,17,11};

// ---------------- prep: breath(noise+kern+conv+stats partial) + phase increments ----------------
__global__ __launch_bounds__(256) void k_prep(const float* __restrict__ bss,
                                              const float* __restrict__ f0,
                                              const float* __restrict__ vr,
                                              const float* __restrict__ vd){
  int b = blockIdx.x / 250, c = blockIdx.x % 250;
  int t0 = c*256, tid = threadIdx.x;
  __shared__ float ns[384];
  __shared__ float kl[129];
  __shared__ float wn[8];
  if (tid < 8){
    int ksz = KSZc[tid];
    float sig = (float)ksz / 6.0f;
    float inv2s2 = 1.0f/(2.0f*sig*sig);
    int ctr = ksz>>1;
    float s = 0.f;
    for (int j=0;j<ksz;j++){ float d = (float)(j - ctr); s += expf(-d*d*inv2s2); }
    wn[tid] = bss[((size_t)b*T_ + T_/2)*8 + tid] / s;
  }
  for (int j = tid; j < 384; j += 256){
    int t = t0 - 64 + j;
    float v = 0.f;
    if (t >= 0 && t < T_) v = bits_to_normal(threefry_bits((uint32_t)(b*T_ + t)));
    ns[j] = v;
  }
  __syncthreads();
  if (tid < 129){
    int tau = tid - 64;
    float acc = 0.f;
    #pragma unroll
    for (int i=0;i<8;i++){
      int ksz = KSZc[i]; int hw = ksz>>1;
      if (tau >= -hw && tau <= hw){
        float sig = (float)ksz/6.0f;
        float inv2s2 = 1.0f/(2.0f*sig*sig);
        acc += expf(-(float)(tau*tau)*inv2s2) * wn[i];
      }
    }
    kl[tid] = acc;
  }
  __syncthreads();
  float acc = 0.f;
  for (int j=0;j<129;j++) acc = fmaf(ns[tid+j], kl[j], acc);
  g_shaped[b*T_ + t0 + tid] = acc;
  double xx = (double)acc;
  double s1 = xx, s2 = xx*xx;
  for (int o=1;o<64;o<<=1){ s1 += __shfl_down(s1,o); s2 += __shfl_down(s2,o); }
  __shared__ double a1[4], a2[4];
  int lane = tid&63, wid = tid>>6;
  if (lane==0){ a1[wid]=s1; a2[wid]=s2; }
  __syncthreads();
  if (tid==0){
    g_part[(b*250+c)*2]   = a1[0]+a1[1]+a1[2]+a1[3];
    g_part[(b*250+c)*2+1] = a2[0]+a2[1]+a2[2]+a2[3];
  }
  // ---- phase increments + harmonic count + 64-chunk sums ----
  int t = t0 + tid;
  int idx = b*T_ + t;
  double tt = (double)t / 44100.0;
  double sv = sin(TWO_PI_D * (double)vr[idx] * tt);
  double lm = (double)vd[idx] * 0.057762265046662105;   // ln2/12
  double vm = exp(sv * lm);
  double f0s = (double)f0[idx];
  double f0v = (f0s > 0.0) ? f0s * vm : f0s;
  int cnt;
  if (f0v <= 0.0) cnt = 96;
  else {
    int n = (int)(22050.0 / f0v);
    if (!((double)n * f0v < 22050.0)) n--;
    if ((double)(n+1) * f0v < 22050.0) n++;
    cnt = (n < 0) ? 0 : ((n > 96) ? 96 : n);
  }
  g_hcnt[idx] = (unsigned char)cnt;
  double v = TWO_PI_D * f0v / 44100.0;
  g_dpf[idx] = (float)v;
  for (int o=1;o<64;o<<=1) v += __shfl_down(v, o);
  if (lane == 0) g_chunksum[b*NCH + c*4 + wid] = v;
}

// ---------------- harmonic additive synth: direct-global amps, gate-skip, cos identity ----------------
__global__ __launch_bounds__(256) void k_signal(const float* __restrict__ amps,
                                                const float* __restrict__ goq,
                                                const float* __restrict__ iph,
                                                float* __restrict__ out_final){
  __shared__ float ph[TT_];
  int b = blockIdx.x / NCH, c = blockIdx.x % NCH;
  int t0 = c*TT_;
  int tid = threadIdx.x;
  if (tid < 64){
    double s = 0.0;
    for (int ch = tid; ch < c; ch += 64) s += g_chunksum[b*NCH + ch];
    for (int o=1;o<64;o<<=1) s += __shfl_xor(s, o);
    double base = s + (double)iph[b];
    int idx = b*T_ + t0 + tid;
    double v = (double)g_dpf[idx];
    for (int o=1;o<64;o<<=1){ double u = __shfl_up(v, o); if (tid >= o) v += u; }
    ph[tid] = (float)fmod(base + v, TWO_PI_D);
    if (c == NCH-1 && tid == 63) out_final[b] = (float)fmod(base + v, TWO_PI_D);
  }
  __syncthreads();
  int tl = tid >> 2, part = tid & 3;
  int idx = b*T_ + t0 + tl;
  float r = ph[tl];
  int hc = (int)g_hcnt[idx];
  float oq = goq[idx];
  // flow-0.5 = (fr<oq) ? -cos(pi*fr/oq)/2 : +cos(pi*(fr-oq)/(1-oq))/2
  float k1 = 3.14159265358979f / oq;
  float k2 = 3.14159265358979f / (1.0f - oq);
  float sum = 0.f;
  const float4* Ar = (const float4*)(amps + ((size_t)b*T_ + t0 + tl)*H_ + part*24);
  int hbase = part*24;
  #pragma unroll
  for (int j4=0;j4<6;j4++){
    int h0 = hbase + j4*4;
    if (h0 >= hc) break;            // amp==0 beyond gate: skip the load entirely
    float4 a4 = Ar[j4];
    float av0[4] = {a4.x, a4.y, a4.z, a4.w};
    #pragma unroll
    for (int e=0;e<4;e++){
      int h = h0 + e;
      float amp = (h < hc) ? av0[e] : 0.0f;
      float nn = (float)(h+1);
      float fr = r * nn * 0.15915494309189535f;
      fr = fr - floorf(fr);
      bool ris = fr < oq;
      float arg = ris ? fr * k1 : (fr - oq) * k2;
      float cv = __cosf(arg);
      float halfs = ris ? -0.5f : 0.5f;
      sum = fmaf(halfs * cv, amp, sum);
    }
  }
  sum += __shfl_xor(sum, 1);
  sum += __shfl_xor(sum, 2);
  if (part == 0) g_signal[idx] = sum;
}

// ---------------- FFT helpers ----------------
template<int SGN>
__device__ __forceinline__ float2* fft512_stages(float2* bufA, float2* bufB, int tid){
  float2* src = bufA; float2* dst = bufB;
  #pragma unroll
  for (int st=0; st<9; st++){
    const int s = 1<<st;
    const int n = 512>>st;
    const int m = n>>1;
    int p = tid >> st;
    int q = tid & (s-1);
    float2 a  = src[q + s*p];
    float2 bb = src[q + s*(p+m)];
    float ang = (float)SGN * ((float)(2.0*M_PI)/(float)n) * (float)p;
    float sw, cw; __sincosf(ang, &sw, &cw);
    dst[q + 2*s*p]     = cadd(a, bb);
    dst[q + 2*s*p + s] = cmul(make_float2(cw, sw), csub(a, bb));
    __syncthreads();
    float2* tp = src; src = dst; dst = tp;
  }
  return src;
}

__device__ __forceinline__ cplx w5k(int k, float sgn){
  const float C[5] = {1.f, 0.30901699f, -0.80901699f, -0.80901699f, 0.30901699f};
  const float S[5] = {0.f, 0.95105652f, 0.58778525f, -0.58778525f, -0.95105652f};
  return make_float2(C[k], sgn*S[k]);
}

template<int SGN>
__device__ __forceinline__ float2* fft125_rows(float2* bufA, float2* bufB, int tid){
  float2* src = bufA; float2* dst = bufB;
  #pragma unroll
  for (int st=0; st<3; st++){
    const int s = (st==0)?1:((st==1)?5:25);
    const int n = (st==0)?125:((st==1)?25:5);
    const int m = n/5;
    if (tid < 200){
      int row = tid/25, w = tid - row*25;
      int p = w/s, q = w - p*s;
      int base = row*125 + q;
      float2 a0 = src[base + s*p];
      float2 a1 = src[base + s*(p+m)];
      float2 a2 = src[base + s*(p+2*m)];
      float2 a3 = src[base + s*(p+3*m)];
      float2 a4 = src[base + s*(p+4*m)];
      #pragma unroll
      for (int r2=0;r2<5;r2++){
        float2 acc = a0;
        acc = cadd(acc, cmul(a1, w5k((1*r2)%5, (float)SGN)));
        acc = cadd(acc, cmul(a2, w5k((2*r2)%5, (float)SGN)));
        acc = cadd(acc, cmul(a3, w5k((3*r2)%5, (float)SGN)));
        acc = cadd(acc, cmul(a4, w5k((4*r2)%5, (float)SGN)));
        float ang = (float)SGN * ((float)(2.0*M_PI)/(float)n) * (float)(p*r2);
        float sw,cw; __sincosf(ang,&sw,&cw);
        dst[base + s*(5*p+r2)] = cmul(make_float2(cw,sw), acc);
      }
    }
    __syncthreads();
    float2* tp = src; src = dst; dst = tp;
  }
  return src;
}

__global__ __launch_bounds__(256) void k_fft512_fwd(){
  int p = blockIdx.x / 125, n1 = blockIdx.x % 125;
  int tid = threadIdx.x;
  __shared__ float2 bufA[512];
  __shared__ float2 bufB[512];
  const float* sa = g_signal + (size_t)(2*p)*T_;
  const float* sb = g_signal + (size_t)(2*p+1)*T_;
  for (int i=tid;i<512;i+=256) bufA[i] = make_float2(sa[n1 + 125*i], sb[n1 + 125*i]);
  __syncthreads();
  float2* res = fft512_stages<-1>(bufA, bufB, tid);
  for (int i=tid;i<512;i+=256){
    float ang = -(float)(2.0*M_PI/64000.0) * (float)(n1*i);
    float sw,cw; __sincosf(ang,&sw,&cw);
    g_W1[((size_t)p*512 + i)*125 + n1] = cmul(make_float2(cw,sw), res[i]);
  }
  if (blockIdx.x < B_){
    int b = blockIdx.x;
    double s1=0.0, s2=0.0;
    if (tid < 250){ s1 = g_part[(b*250+tid)*2]; s2 = g_part[(b*250+tid)*2+1]; }
    for (int o=1;o<64;o<<=1){ s1 += __shfl_down(s1,o); s2 += __shfl_down(s2,o); }
    __shared__ double a1[4], a2[4];
    int lane = tid&63, wid = tid>>6;
    if (lane==0){ a1[wid]=s1; a2[wid]=s2; }
    __syncthreads();
    if (tid==0){
      double S1=a1[0]+a1[1]+a1[2]+a1[3], S2=a2[0]+a2[1]+a2[2]+a2[3];
      double mean = S1 / (double)T_;
      double var = (S2 - (double)T_*mean*mean) / (double)(T_-1);
      if (var < 0.0) var = 0.0;
      double rstd = 1.0/(sqrt(var) + 1e-8);
      g_stats[b*2] = mean; g_stats[b*2+1] = rstd;
    }
  }
}

__global__ __launch_bounds__(256) void k_fft125_mid(const float* __restrict__ ffq,
                                                    const float* __restrict__ fbw,
                                                    const float* __restrict__ fgn){
  int p = blockIdx.x / 64;
  int j = blockIdx.x % 64;
  int tid = threadIdx.x;
  __shared__ float2 bufA[1000];
  __shared__ float2 bufB[1000];
  int k2r[8];
  #pragma unroll
  for (int l=0;l<8;l++){
    int k2;
    if (l < 4) k2 = 4*j + l;
    else if (j==0 && l==4) k2 = 256;
    else k2 = 512 - 4*j - (l-4);
    k2r[l] = k2;
  }
  for (int i=tid;i<1000;i+=256){
    int l = i/125, n1 = i - l*125;
    bufA[i] = g_W1[((size_t)p*512 + k2r[l])*125 + n1];
  }
  float fca[4], bwa[4], ga[4], fcb[4], bwb[4], gb[4];
  int ba = 2*p, bb = 2*p+1;
  #pragma unroll
  for (int q=0;q<4;q++){
    size_t ia = ((size_t)ba*T_ + T_/2)*4 + q;
    size_t ib = ((size_t)bb*T_ + T_/2)*4 + q;
    fca[q]=ffq[ia]; bwa[q]=fbw[ia]; ga[q]=fgn[ia];
    fcb[q]=ffq[ib]; bwb[q]=fbw[ib]; gb[q]=fgn[ib];
  }
  __syncthreads();
  float2* X = fft125_rows<-1>(bufA, bufB, tid);
  float2* Y = (X == bufA) ? bufB : bufA;
  for (int i=tid;i<1000;i+=256){
    int l = i/125, k1 = i - l*125;
    int k2 = k2r[l];
    int lm = ((j==0) && (l==0 || l==4)) ? l : (l^4);
    int k1m = (k2 == 0) ? ((k1==0)?0:(125-k1)) : (124-k1);
    float2 Z1 = X[l*125 + k1];
    float2 Z2 = X[lm*125 + k1m];
    float xax = 0.5f*(Z1.x + Z2.x), xay = 0.5f*(Z1.y - Z2.y);
    float xbx = 0.5f*(Z1.y + Z2.y), xby = -0.5f*(Z1.x - Z2.x);
    int f = k2 + 512*k1;
    int fi = (f <= 32000) ? f : (64000 - f);
    float freq = (float)fi * 0.6890625f;
    float ra = 0.f, rb = 0.f;
    #pragma unroll
    for (int q=0;q<4;q++){
      float da = (freq - fca[q]) / (bwa[q]*0.5f);
      ra += ga[q] / (1.0f + da*da);
      float db = (freq - fcb[q]) / (bwb[q]*0.5f);
      rb += gb[q] / (1.0f + db*db);
    }
    float yax = ra*xax, yay = ra*xay;
    float ybx = rb*xbx, yby = rb*xby;
    Y[i] = make_float2(yax - yby, yay + ybx);
  }
  __syncthreads();
  float2* res2 = fft125_rows<1>(Y, X, tid);
  for (int i=tid;i<1000;i+=256){
    int l = i/125, n1 = i - l*125;
    int k2 = k2r[l];
    float ang = (float)(2.0*M_PI/64000.0) * (float)(n1*k2);
    float sw,cw; __sincosf(ang,&sw,&cw);
    g_Z[((size_t)p*125 + n1)*512 + k2] = cmul(make_float2(cw,sw), res2[i]);
  }
}

__global__ __launch_bounds__(256) void k_fft512_inv(const float* __restrict__ brth,
                                                    float* __restrict__ outp){
  int p = blockIdx.x / 125, n1 = blockIdx.x % 125;
  int tid = threadIdx.x;
  __shared__ float2 bufA[512];
  __shared__ float2 bufB[512];
  const float2* gin = g_Z + ((size_t)p*125 + n1)*512;
  for (int i=tid;i<512;i+=256) bufA[i] = gin[i];
  __syncthreads();
  float2* res = fft512_stages<1>(bufA, bufB, tid);
  int ba = 2*p, bb = 2*p+1;
  float mean_a = (float)g_stats[ba*2], rstd_a = (float)g_stats[ba*2+1];
  float mean_b = (float)g_stats[bb*2], rstd_b = (float)g_stats[bb*2+1];
  for (int i=tid;i<512;i+=256){
    int t = n1 + 125*i;
    float2 v = res[i];
    {
      int idx = ba*T_ + t;
      float filt = v.x * (1.0f/64000.0f);
      float br = brth[idx];
      float breath = (g_shaped[idx] - mean_a) * rstd_a;
      outp[idx] = filt*(1.0f - br) + breath*br;
    }
    {
      int idx = bb*T_ + t;
      float filt = v.y * (1.0f/64000.0f);
      float br = brth[idx];
      float breath = (g_shaped[idx] - mean_b) * rstd_b;
      outp[idx] = filt*(1.0f - br) + breath*br;
    }
  }
}

extern "C" void kernel_launch(void* const* d_in, const int* in_sizes, int n_in,
                              void* d_out, int out_size, void* d_ws, size_t ws_size,
                              hipStream_t stream){
  (void)in_sizes; (void)n_in; (void)out_size; (void)d_ws; (void)ws_size;
  const float* f0   = (const float*)d_in[0];
  const float* amps = (const float*)d_in[1];
  const float* vr   = (const float*)d_in[2];
  const float* vd   = (const float*)d_in[3];
  const float* ffq  = (const float*)d_in[4];
  const float* fbw  = (const float*)d_in[5];
  const float* fgn  = (const float*)d_in[6];
  const float* goq  = (const float*)d_in[7];
  const float* brth = (const float*)d_in[9];
  const float* bss  = (const float*)d_in[10];
  const float* iph  = (const float*)d_in[11];
  float* out = (float*)d_out;
  float* out_final = out + (size_t)B_*T_;

  k_prep<<<B_*250,256,0,stream>>>(bss, f0, vr, vd);
  k_signal<<<B_*NCH,256,0,stream>>>(amps, goq, iph, out_final);
  k_fft512_fwd<<<250,256,0,stream>>>();
  k_fft125_mid<<<128,256,0,stream>>>(ffq, fbw, fgn);
  k_fft512_inv<<<250,256,0,stream>>>(brth, out);
}

// Round 13
// 63.428 us; speedup vs baseline: 2.4445x; 1.1771x over previous
//
#include <hip/hip_runtime.h>
#include <math.h>
#include <stdint.h>

#define B_ 4
#define T_ 64000
#define H_ 96
#define NCH 1000
#define TT_ 64
#define TWO_PI_D 6.283185307179586

typedef float2 cplx;
__device__ __forceinline__ cplx cadd(cplx a, cplx b){ return make_float2(a.x+b.x, a.y+b.y); }
__device__ __forceinline__ cplx csub(cplx a, cplx b){ return make_float2(a.x-b.x, a.y-b.y); }
__device__ __forceinline__ cplx cmul(cplx a, cplx b){ return make_float2(a.x*b.x - a.y*b.y, a.x*b.y + a.y*b.x); }

// ---------------- static scratch ----------------
__device__ float  g_dpf[B_*T_];
__device__ unsigned char g_hcnt[B_*T_];
__device__ float  g_signal[B_*T_];
__device__ float  g_shaped[B_*T_];
__device__ float2 g_W1[2*512*125];
__device__ float2 g_Z[2*125*512];
__device__ double g_chunksum[B_*NCH];
__device__ double g_stats[B_*2];
__device__ double g_part[B_*250*2];

// ---------------- fast f64 transcendentals (args bounded by problem) ----------------
// sin(x) for 0 <= x <= 64: 2-term Cody-Waite + fdlibm polys. |err| ~1e-16 rel.
__device__ __forceinline__ double fsin64(double x){
  double z = x * 0.63661977236758138243;      // 2/pi
  double fn = floor(z + 0.5);
  int k = (int)fn;
  const double p1 = 1.57079632673412561417e+00;   // pio2_1 (33 bits)
  const double p2 = 6.07710050650619224932e-11;   // pio2_1t
  double r = x - fn*p1;
  r = r - fn*p2;
  double s = r*r;
  double ps = 1.58969099521155010221e-10;
  ps = ps*s - 2.50507602534068634195e-08;
  ps = ps*s + 2.75573137070700676789e-06;
  ps = ps*s - 1.98412698298579493134e-04;
  ps = ps*s + 8.33333333332248946124e-03;
  ps = ps*s - 1.66666666666666324348e-01;
  double sr = r + r*s*ps;
  double pc = -1.13596475577881948265e-11;
  pc = pc*s + 2.08757232129817482790e-09;
  pc = pc*s - 2.75573143513906633035e-07;
  pc = pc*s + 2.48015872894767294178e-05;
  pc = pc*s - 1.38888888888741095749e-03;
  pc = pc*s + 4.16666666666666019037e-02;
  double cr = 1.0 - 0.5*s + s*s*pc;
  int m = k & 3;
  return (m==0) ? sr : (m==1) ? cr : (m==2) ? -sr : -cr;
}

// exp(x) for |x| <= 0.0116: degree-7 Taylor (rel err ~1e-20)
__device__ __forceinline__ double fexp_small(double x){
  double p = 1.9841269841269841e-04;   // 1/5040
  p = p*x + 1.3888888888888889e-03;    // 1/720
  p = p*x + 8.3333333333333332e-03;    // 1/120
  p = p*x + 4.1666666666666664e-02;    // 1/24
  p = p*x + 1.6666666666666666e-01;    // 1/6
  p = p*x + 0.5;
  p = p*x + 1.0;
  p = p*x + 1.0;
  return p;
}

// ---------------- threefry (partitionable, out0^out1) ----------------
__device__ __forceinline__ uint32_t rotl32(uint32_t x, int r){ return (x<<r)|(x>>(32-r)); }

__device__ __forceinline__ uint32_t threefry_bits(uint32_t i){
  uint32_t x0 = 0u, x1 = i;
  const uint32_t ks0 = 0u, ks1 = 42u, ks2 = 0u ^ 42u ^ 0x1BD11BDAu;
  x0 += ks0; x1 += ks1;
  #define TFR(r) { x0 += x1; x1 = rotl32(x1, r); x1 ^= x0; }
  TFR(13) TFR(15) TFR(26) TFR(6)   x0 += ks1; x1 += ks2 + 1u;
  TFR(17) TFR(29) TFR(16) TFR(24)  x0 += ks2; x1 += ks0 + 2u;
  TFR(13) TFR(15) TFR(26) TFR(6)   x0 += ks0; x1 += ks1 + 3u;
  TFR(17) TFR(29) TFR(16) TFR(24)  x0 += ks1; x1 += ks2 + 4u;
  TFR(13) TFR(15) TFR(26) TFR(6)   x0 += ks2; x1 += ks0 + 5u;
  #undef TFR
  return x0 ^ x1;
}

__device__ __forceinline__ float bits_to_normal(uint32_t bits){
  uint32_t mbits = (bits >> 9) | 0x3F800000u;
  float f = __uint_as_float(mbits) - 1.0f;
  const float lo = -0.99999994f;
  float x = f * 2.0f + lo;
  x = fmaxf(lo, x);
  float w = -log1pf(-x*x);
  float p;
  if (w < 5.0f){
    w -= 2.5f;
    p = 2.81022636e-08f;
    p = fmaf(p, w, 3.43273939e-07f);
    p = fmaf(p, w, -3.5233877e-06f);
    p = fmaf(p, w, -4.39150654e-06f);
    p = fmaf(p, w, 0.00021858087f);
    p = fmaf(p, w, -0.00125372503f);
    p = fmaf(p, w, -0.00417768164f);
    p = fmaf(p, w, 0.246640727f);
    p = fmaf(p, w, 1.50140941f);
  } else {
    w = sqrtf(w) - 3.0f;
    p = -0.000200214257f;
    p = fmaf(p, w, 0.000100950558f);
    p = fmaf(p, w, 0.00134934322f);
    p = fmaf(p, w, -0.00367342844f);
    p = fmaf(p, w, 0.00573950773f);
    p = fmaf(p, w, -0.0076224613f);
    p = fmaf(p, w, 0.00943887047f);
    p = fmaf(p, w, 1.00167406f);
    p = fmaf(p, w, 2.83297682f);
  }
  return 1.4142135623730951f * (p * x);
}

__constant__ int KSZc[8] = {129,91,65,45,33,23,17,11};

// ---------------- prep: breath(noise+kern+conv+stats partial) + phase increments ----------------
__global__ __launch_bounds__(256) void k_prep(const float* __restrict__ bss,
                                              const float* __restrict__ f0,
                                              const float* __restrict__ vr,
                                              const float* __restrict__ vd){
  int b = blockIdx.x / 250, c = blockIdx.x % 250;
  int t0 = c*256, tid = threadIdx.x;
  __shared__ float ns[384];
  __shared__ float kl[129];
  __shared__ float wn[8];
  // parallel norm sums: kernel i = tid>>5, lanes tid&31 each sum <=5 strided terms
  {
    int i = tid >> 5, l32 = tid & 31;
    int ksz = KSZc[i];
    float sig = (float)ksz / 6.0f;
    float inv2s2 = 1.0f/(2.0f*sig*sig);
    int ctr = ksz>>1;
    float s = 0.f;
    for (int j = l32; j < ksz; j += 32){
      float d = (float)(j - ctr);
      s += expf(-d*d*inv2s2);
    }
    #pragma unroll
    for (int o=1;o<32;o<<=1) s += __shfl_xor(s, o);
    if (l32 == 0) wn[i] = bss[((size_t)b*T_ + T_/2)*8 + i] / s;
  }
  for (int j = tid; j < 384; j += 256){
    int t = t0 - 64 + j;
    float v = 0.f;
    if (t >= 0 && t < T_) v = bits_to_normal(threefry_bits((uint32_t)(b*T_ + t)));
    ns[j] = v;
  }
  __syncthreads();
  if (tid < 129){
    int tau = tid - 64;
    float acc = 0.f;
    #pragma unroll
    for (int i=0;i<8;i++){
      int ksz = KSZc[i]; int hw = ksz>>1;
      if (tau >= -hw && tau <= hw){
        float sig = (float)ksz/6.0f;
        float inv2s2 = 1.0f/(2.0f*sig*sig);
        acc += expf(-(float)(tau*tau)*inv2s2) * wn[i];
      }
    }
    kl[tid] = acc;
  }
  __syncthreads();
  // conv: 4 independent partial chains
  float a0=0.f, a1v=0.f, a2v=0.f, a3v=0.f;
  for (int j=0;j<128;j+=4){
    a0  = fmaf(ns[tid+j],   kl[j],   a0);
    a1v = fmaf(ns[tid+j+1], kl[j+1], a1v);
    a2v = fmaf(ns[tid+j+2], kl[j+2], a2v);
    a3v = fmaf(ns[tid+j+3], kl[j+3], a3v);
  }
  a0 = fmaf(ns[tid+128], kl[128], a0);
  float acc = (a0+a1v)+(a2v+a3v);
  g_shaped[b*T_ + t0 + tid] = acc;
  double xx = (double)acc;
  double s1 = xx, s2 = xx*xx;
  for (int o=1;o<64;o<<=1){ s1 += __shfl_down(s1,o); s2 += __shfl_down(s2,o); }
  __shared__ double pa1[4], pa2[4];
  int lane = tid&63, wid = tid>>6;
  if (lane==0){ pa1[wid]=s1; pa2[wid]=s2; }
  __syncthreads();
  if (tid==0){
    g_part[(b*250+c)*2]   = pa1[0]+pa1[1]+pa1[2]+pa1[3];
    g_part[(b*250+c)*2+1] = pa2[0]+pa2[1]+pa2[2]+pa2[3];
  }
  // ---- phase increments + harmonic count + 64-chunk sums ----
  int t = t0 + tid;
  int idx = b*T_ + t;
  double tt = (double)t * 2.2675736961451248e-05;      // 1/44100
  double sv = fsin64(TWO_PI_D * (double)vr[idx] * tt);
  double lm = (double)vd[idx] * 0.057762265046662105;  // ln2/12
  double vm = fexp_small(sv * lm);
  double f0s = (double)f0[idx];
  double f0v = (f0s > 0.0) ? f0s * vm : f0s;
  int cnt;
  if (f0v <= 0.0) cnt = 96;
  else {
    int n = (int)(22050.0f / (float)f0v);
    if (!((double)n * f0v < 22050.0)) n--;
    if ((double)(n+1) * f0v < 22050.0) n++;
    cnt = (n < 0) ? 0 : ((n > 96) ? 96 : n);
  }
  g_hcnt[idx] = (unsigned char)cnt;
  double v = f0v * 1.4247585730565955e-04;             // 2*pi/44100
  g_dpf[idx] = (float)v;
  for (int o=1;o<64;o<<=1) v += __shfl_down(v, o);
  if (lane == 0) g_chunksum[b*NCH + c*4 + wid] = v;
}

// ---------------- harmonic additive synth: direct-global amps, gate-skip, cos identity ----------------
__global__ __launch_bounds__(256) void k_signal(const float* __restrict__ amps,
                                                const float* __restrict__ goq,
                                                const float* __restrict__ iph,
                                                float* __restrict__ out_final){
  __shared__ float ph[TT_];
  int b = blockIdx.x / NCH, c = blockIdx.x % NCH;
  int t0 = c*TT_;
  int tid = threadIdx.x;
  if (tid < 64){
    double s = 0.0;
    for (int ch = tid; ch < c; ch += 64) s += g_chunksum[b*NCH + ch];
    for (int o=1;o<64;o<<=1) s += __shfl_xor(s, o);
    double base = s + (double)iph[b];
    int idx = b*T_ + t0 + tid;
    double v = (double)g_dpf[idx];
    for (int o=1;o<64;o<<=1){ double u = __shfl_up(v, o); if (tid >= o) v += u; }
    ph[tid] = (float)fmod(base + v, TWO_PI_D);
    if (c == NCH-1 && tid == 63) out_final[b] = (float)fmod(base + v, TWO_PI_D);
  }
  __syncthreads();
  int tl = tid >> 2, part = tid & 3;
  int idx = b*T_ + t0 + tl;
  float r = ph[tl];
  int hc = (int)g_hcnt[idx];
  float oq = goq[idx];
  float k1 = 3.14159265358979f / oq;
  float k2 = 3.14159265358979f / (1.0f - oq);
  float sum = 0.f;
  const float4* Ar = (const float4*)(amps + ((size_t)b*T_ + t0 + tl)*H_ + part*24);
  int hbase = part*24;
  #pragma unroll
  for (int j4=0;j4<6;j4++){
    int h0 = hbase + j4*4;
    if (h0 >= hc) break;
    float4 a4 = Ar[j4];
    float av0[4] = {a4.x, a4.y, a4.z, a4.w};
    #pragma unroll
    for (int e=0;e<4;e++){
      int h = h0 + e;
      float amp = (h < hc) ? av0[e] : 0.0f;
      float nn = (float)(h+1);
      float fr = r * nn * 0.15915494309189535f;
      fr = fr - floorf(fr);
      bool ris = fr < oq;
      float arg = ris ? fr * k1 : (fr - oq) * k2;
      float cv = __cosf(arg);
      float halfs = ris ? -0.5f : 0.5f;
      sum = fmaf(halfs * cv, amp, sum);
    }
  }
  sum += __shfl_xor(sum, 1);
  sum += __shfl_xor(sum, 2);
  if (part == 0) g_signal[idx] = sum;
}

// ---------------- FFT helpers ----------------
template<int SGN>
__device__ __forceinline__ float2* fft512_stages(float2* bufA, float2* bufB, int tid){
  float2* src = bufA; float2* dst = bufB;
  #pragma unroll
  for (int st=0; st<9; st++){
    const int s = 1<<st;
    const int n = 512>>st;
    const int m = n>>1;
    int p = tid >> st;
    int q = tid & (s-1);
    float2 a  = src[q + s*p];
    float2 bb = src[q + s*(p+m)];
    float ang = (float)SGN * ((float)(2.0*M_PI)/(float)n) * (float)p;
    float sw, cw; __sincosf(ang, &sw, &cw);
    dst[q + 2*s*p]     = cadd(a, bb);
    dst[q + 2*s*p + s] = cmul(make_float2(cw, sw), csub(a, bb));
    __syncthreads();
    float2* tp = src; src = dst; dst = tp;
  }
  return src;
}

__device__ __forceinline__ cplx w5k(int k, float sgn){
  const float C[5] = {1.f, 0.30901699f, -0.80901699f, -0.80901699f, 0.30901699f};
  const float S[5] = {0.f, 0.95105652f, 0.58778525f, -0.58778525f, -0.95105652f};
  return make_float2(C[k], sgn*S[k]);
}

template<int SGN>
__device__ __forceinline__ float2* fft125_rows(float2* bufA, float2* bufB, int tid){
  float2* src = bufA; float2* dst = bufB;
  #pragma unroll
  for (int st=0; st<3; st++){
    const int s = (st==0)?1:((st==1)?5:25);
    const int n = (st==0)?125:((st==1)?25:5);
    const int m = n/5;
    if (tid < 200){
      int row = tid/25, w = tid - row*25;
      int p = w/s, q = w - p*s;
      int base = row*125 + q;
      float2 a0 = src[base + s*p];
      float2 a1 = src[base + s*(p+m)];
      float2 a2 = src[base + s*(p+2*m)];
      float2 a3 = src[base + s*(p+3*m)];
      float2 a4 = src[base + s*(p+4*m)];
      #pragma unroll
      for (int r2=0;r2<5;r2++){
        float2 acc = a0;
        acc = cadd(acc, cmul(a1, w5k((1*r2)%5, (float)SGN)));
        acc = cadd(acc, cmul(a2, w5k((2*r2)%5, (float)SGN)));
        acc = cadd(acc, cmul(a3, w5k((3*r2)%5, (float)SGN)));
        acc = cadd(acc, cmul(a4, w5k((4*r2)%5, (float)SGN)));
        float ang = (float)SGN * ((float)(2.0*M_PI)/(float)n) * (float)(p*r2);
        float sw,cw; __sincosf(ang,&sw,&cw);
        dst[base + s*(5*p+r2)] = cmul(make_float2(cw,sw), acc);
      }
    }
    __syncthreads();
    float2* tp = src; src = dst; dst = tp;
  }
  return src;
}

__global__ __launch_bounds__(256) void k_fft512_fwd(){
  int p = blockIdx.x / 125, n1 = blockIdx.x % 125;
  int tid = threadIdx.x;
  __shared__ float2 bufA[512];
  __shared__ float2 bufB[512];
  const float* sa = g_signal + (size_t)(2*p)*T_;
  const float* sb = g_signal + (size_t)(2*p+1)*T_;
  for (int i=tid;i<512;i+=256) bufA[i] = make_float2(sa[n1 + 125*i], sb[n1 + 125*i]);
  __syncthreads();
  float2* res = fft512_stages<-1>(bufA, bufB, tid);
  for (int i=tid;i<512;i+=256){
    float ang = -(float)(2.0*M_PI/64000.0) * (float)(n1*i);
    float sw,cw; __sincosf(ang,&sw,&cw);
    g_W1[((size_t)p*512 + i)*125 + n1] = cmul(make_float2(cw,sw), res[i]);
  }
  if (blockIdx.x < B_){
    int b = blockIdx.x;
    double s1=0.0, s2=0.0;
    if (tid < 250){ s1 = g_part[(b*250+tid)*2]; s2 = g_part[(b*250+tid)*2+1]; }
    for (int o=1;o<64;o<<=1){ s1 += __shfl_down(s1,o); s2 += __shfl_down(s2,o); }
    __shared__ double a1[4], a2[4];
    int lane = tid&63, wid = tid>>6;
    if (lane==0){ a1[wid]=s1; a2[wid]=s2; }
    __syncthreads();
    if (tid==0){
      double S1=a1[0]+a1[1]+a1[2]+a1[3], S2=a2[0]+a2[1]+a2[2]+a2[3];
      double mean = S1 / (double)T_;
      double var = (S2 - (double)T_*mean*mean) / (double)(T_-1);
      if (var < 0.0) var = 0.0;
      double rstd = 1.0/(sqrt(var) + 1e-8);
      g_stats[b*2] = mean; g_stats[b*2+1] = rstd;
    }
  }
}

__global__ __launch_bounds__(256) void k_fft125_mid(const float* __restrict__ ffq,
                                                    const float* __restrict__ fbw,
                                                    const float* __restrict__ fgn){
  int p = blockIdx.x / 64;
  int j = blockIdx.x % 64;
  int tid = threadIdx.x;
  __shared__ float2 bufA[1000];
  __shared__ float2 bufB[1000];
  int k2r[8];
  #pragma unroll
  for (int l=0;l<8;l++){
    int k2;
    if (l < 4) k2 = 4*j + l;
    else if (j==0 && l==4) k2 = 256;
    else k2 = 512 - 4*j - (l-4);
    k2r[l] = k2;
  }
  for (int i=tid;i<1000;i+=256){
    int l = i/125, n1 = i - l*125;
    bufA[i] = g_W1[((size_t)p*512 + k2r[l])*125 + n1];
  }
  float fca[4], bwa[4], ga[4], fcb[4], bwb[4], gb[4];
  int ba = 2*p, bb = 2*p+1;
  #pragma unroll
  for (int q=0;q<4;q++){
    size_t ia = ((size_t)ba*T_ + T_/2)*4 + q;
    size_t ib = ((size_t)bb*T_ + T_/2)*4 + q;
    fca[q]=ffq[ia]; bwa[q]=fbw[ia]; ga[q]=fgn[ia];
    fcb[q]=ffq[ib]; bwb[q]=fbw[ib]; gb[q]=fgn[ib];
  }
  __syncthreads();
  float2* X = fft125_rows<-1>(bufA, bufB, tid);
  float2* Y = (X == bufA) ? bufB : bufA;
  for (int i=tid;i<1000;i+=256){
    int l = i/125, k1 = i - l*125;
    int k2 = k2r[l];
    int lm = ((j==0) && (l==0 || l==4)) ? l : (l^4);
    int k1m = (k2 == 0) ? ((k1==0)?0:(125-k1)) : (124-k1);
    float2 Z1 = X[l*125 + k1];
    float2 Z2 = X[lm*125 + k1m];
    float xax = 0.5f*(Z1.x + Z2.x), xay = 0.5f*(Z1.y - Z2.y);
    float xbx = 0.5f*(Z1.y + Z2.y), xby = -0.5f*(Z1.x - Z2.x);
    int f = k2 + 512*k1;
    int fi = (f <= 32000) ? f : (64000 - f);
    float freq = (float)fi * 0.6890625f;
    float ra = 0.f, rb = 0.f;
    #pragma unroll
    for (int q=0;q<4;q++){
      float da = (freq - fca[q]) / (bwa[q]*0.5f);
      ra += ga[q] / (1.0f + da*da);
      float db = (freq - fcb[q]) / (bwb[q]*0.5f);
      rb += gb[q] / (1.0f + db*db);
    }
    float yax = ra*xax, yay = ra*xay;
    float ybx = rb*xbx, yby = rb*xby;
    Y[i] = make_float2(yax - yby, yay + ybx);
  }
  __syncthreads();
  float2* res2 = fft125_rows<1>(Y, X, tid);
  for (int i=tid;i<1000;i+=256){
    int l = i/125, n1 = i - l*125;
    int k2 = k2r[l];
    float ang = (float)(2.0*M_PI/64000.0) * (float)(n1*k2);
    float sw,cw; __sincosf(ang,&sw,&cw);
    g_Z[((size_t)p*125 + n1)*512 + k2] = cmul(make_float2(cw,sw), res2[i]);
  }
}

__global__ __launch_bounds__(256) void k_fft512_inv(const float* __restrict__ brth,
                                                    float* __restrict__ outp){
  int p = blockIdx.x / 125, n1 = blockIdx.x % 125;
  int tid = threadIdx.x;
  __shared__ float2 bufA[512];
  __shared__ float2 bufB[512];
  const float2* gin = g_Z + ((size_t)p*125 + n1)*512;
  for (int i=tid;i<512;i+=256) bufA[i] = gin[i];
  __syncthreads();
  float2* res = fft512_stages<1>(bufA, bufB, tid);
  int ba = 2*p, bb = 2*p+1;
  float mean_a = (float)g_stats[ba*2], rstd_a = (float)g_stats[ba*2+1];
  float mean_b = (float)g_stats[bb*2], rstd_b = (float)g_stats[bb*2+1];
  for (int i=tid;i<512;i+=256){
    int t = n1 + 125*i;
    float2 v = res[i];
    {
      int idx = ba*T_ + t;
      float filt = v.x * (1.0f/64000.0f);
      float br = brth[idx];
      float breath = (g_shaped[idx] - mean_a) * rstd_a;
      outp[idx] = filt*(1.0f - br) + breath*br;
    }
    {
      int idx = bb*T_ + t;
      float filt = v.y * (1.0f/64000.0f);
      float br = brth[idx];
      float breath = (g_shaped[idx] - mean_b) * rstd_b;
      outp[idx] = filt*(1.0f - br) + breath*br;
    }
  }
}

extern "C" void kernel_launch(void* const* d_in, const int* in_sizes, int n_in,
                              void* d_out, int out_size, void* d_ws, size_t ws_size,
                              hipStream_t stream){
  (void)in_sizes; (void)n_in; (void)out_size; (void)d_ws; (void)ws_size;
  const float* f0   = (const float*)d_in[0];
  const float* amps = (const float*)d_in[1];
  const float* vr   = (const float*)d_in[2];
  const float* vd   = (const float*)d_in[3];
  const float* ffq  = (const float*)d_in[4];
  const float* fbw  = (const float*)d_in[5];
  const float* fgn  = (const float*)d_in[6];
  const float* goq  = (const float*)d_in[7];
  const float* brth = (const float*)d_in[9];
  const float* bss  = (const float*)d_in[10];
  const float* iph  = (const float*)d_in[11];
  float* out = (float*)d_out;
  float* out_final = out + (size_t)B_*T_;

  k_prep<<<B_*250,256,0,stream>>>(bss, f0, vr, vd);
  k_signal<<<B_*NCH,256,0,stream>>>(amps, goq, iph, out_final);
  k_fft512_fwd<<<250,256,0,stream>>>();
  k_fft125_mid<<<128,256,0,stream>>>(ffq, fbw, fgn);
  k_fft512_inv<<<250,256,0,stream>>>(brth, out);
}